// Round 2
// baseline (406.016 us; speedup 1.0000x reference)
//
#include <hip/hip_runtime.h>

// Problem constants
// B=2048 patients, K=4, PAIRS=6 -> P=12288 pairs, C=1280, K_gemm=2560
// ii = [0,0,0,1,1,2], jj = [1,2,3,2,3,3]  (triu_indices(4,1))
// masks: jax threefry2x32 key(0,42), shape (5,12288,1280), PARTITIONABLE scheme:
//   bits[i] = o0 ^ o1 where (o0,o1) = threefry2x32(key, (hi32(i), lo32(i))), i = flat idx
//   bernoulli(0.5) success == MSB(bits)==0

typedef __attribute__((ext_vector_type(8))) short short8;
typedef __attribute__((ext_vector_type(4))) float f32x4;

#define PLANE 15728640u      // P*C = 12288*1280 (stride between dropout planes)

__device__ __forceinline__ unsigned short f2bf(float f) {
  unsigned int u = __builtin_bit_cast(unsigned int, f);
  u = (u + 0x7FFFu + ((u >> 16) & 1u)) >> 16;   // RNE
  return (unsigned short)u;
}
__device__ __forceinline__ float bf2f(unsigned short h) {
  unsigned int u = ((unsigned int)h) << 16;
  return __builtin_bit_cast(float, u);
}

// ---------------- kernel 0: init output with biases ----------------
__global__ void init_out(float* __restrict__ out, const float* __restrict__ b0,
                         const float* __restrict__ b1, const float* __restrict__ b2) {
  int i = blockIdx.x * 256 + threadIdx.x;
  if (i < 2048 * 3) {
    int h = i % 3;
    out[i] = (h == 0) ? b0[0] : ((h == 1) ? b1[0] : b2[0]);
  }
}

// ---------------- kernel 1a: x fp32 -> bf16 ----------------
__global__ void conv_x(const float* __restrict__ x, unsigned short* __restrict__ xb) {
  int i = (blockIdx.x * 256 + threadIdx.x) * 4;   // 10,485,760 elems total
  float4 v = *(const float4*)(x + i);
  ushort4 o;
  o.x = f2bf(v.x); o.y = f2bf(v.y); o.z = f2bf(v.z); o.w = f2bf(v.w);
  *(ushort4*)(xb + i) = o;
}

// ---------------- kernel 1b: Wc (C,C,2) -> W' [1280][2560] bf16 (B^T, K-major) ----
__global__ void conv_w(const float* __restrict__ Wc, unsigned short* __restrict__ Wb) {
  int idx = blockIdx.x * 256 + threadIdx.x;       // 3,276,800 total
  int n = idx / 2560;
  int k = idx - n * 2560;
  int side = (k >= 1280) ? 1 : 0;
  int cin = k - side * 1280;
  Wb[idx] = f2bf(Wc[n * 2560 + cin * 2 + side]);
}

// ---------------- kernel 2: GEMM  xc = relu(X' @ W'^T + bc), bf16 MFMA ----------
// M=12288, N=1280, K=2560. Tile 128x128, BK=32, 4 waves (2x2), 4x4 16x16 tiles/wave.
#define LDA 40   // padded LDS row length (ushorts)
__global__ __launch_bounds__(256) void gemm_relu(
    const unsigned short* __restrict__ Xb,   // [8192][1280] bf16
    const unsigned short* __restrict__ Wb,   // [1280][2560] bf16
    const float* __restrict__ bc,
    unsigned short* __restrict__ Xc)         // [12288][1280] bf16
{
  __shared__ unsigned short sA[128 * LDA];
  __shared__ unsigned short sB[128 * LDA];
  const int t = threadIdx.x;
  const int mblk = blockIdx.x % 96;
  const int nblk = blockIdx.x / 96;
  const int p0 = mblk * 128, n0 = nblk * 128;
  const int lane = t & 63, w = t >> 6;
  const int wr = w >> 1, wc = w & 1;

  const int r0 = t >> 2, q = t & 3;
  const int p_0 = p0 + r0, p_1 = p0 + r0 + 64;
  const int bA0 = p_0 / 6, pr0 = p_0 - bA0 * 6;
  const int bA1 = p_1 / 6, pr1 = p_1 - bA1 * 6;
  const int rA0 = bA0 * 4 + ((0x211000 >> (4 * pr0)) & 7);
  const int rB0 = bA0 * 4 + ((0x332321 >> (4 * pr0)) & 7);
  const int rA1 = bA1 * 4 + ((0x211000 >> (4 * pr1)) & 7);
  const int rB1 = bA1 * 4 + ((0x332321 >> (4 * pr1)) & 7);

  f32x4 acc[4][4];
#pragma unroll
  for (int i = 0; i < 4; i++)
#pragma unroll
    for (int j = 0; j < 4; j++) acc[i][j] = (f32x4){0.f, 0.f, 0.f, 0.f};

  const int mrow = lane & 15;
  const int koff = (lane >> 4) * 8;

  for (int k0 = 0; k0 < 2560; k0 += 32) {
    const int side = (k0 >= 1280);
    const int kk = k0 - (side ? 1280 : 0) + q * 8;
    const int sr0 = side ? rB0 : rA0;
    const int sr1 = side ? rB1 : rA1;
    uint4 a0v = *(const uint4*)(Xb + sr0 * 1280 + kk);
    uint4 a1v = *(const uint4*)(Xb + sr1 * 1280 + kk);
    uint4 b0v = *(const uint4*)(Wb + (n0 + r0) * 2560 + k0 + q * 8);
    uint4 b1v = *(const uint4*)(Wb + (n0 + r0 + 64) * 2560 + k0 + q * 8);
    __syncthreads();
    *(uint4*)(sA + r0 * LDA + q * 8) = a0v;
    *(uint4*)(sA + (r0 + 64) * LDA + q * 8) = a1v;
    *(uint4*)(sB + r0 * LDA + q * 8) = b0v;
    *(uint4*)(sB + (r0 + 64) * LDA + q * 8) = b1v;
    __syncthreads();

    short8 af[4], bf[4];
#pragma unroll
    for (int i = 0; i < 4; i++)
      af[i] = *(const short8*)(sA + (wr * 64 + i * 16 + mrow) * LDA + koff);
#pragma unroll
    for (int j = 0; j < 4; j++)
      bf[j] = *(const short8*)(sB + (wc * 64 + j * 16 + mrow) * LDA + koff);
#pragma unroll
    for (int i = 0; i < 4; i++)
#pragma unroll
      for (int j = 0; j < 4; j++)
        acc[i][j] = __builtin_amdgcn_mfma_f32_16x16x32_bf16(af[i], bf[j], acc[i][j], 0, 0, 0);
  }

  // epilogue: D layout col=lane&15, row=(lane>>4)*4+reg  [measured m89/m91]
  const int mq = (lane >> 4) * 4;
  const int nn = lane & 15;
#pragma unroll
  for (int j = 0; j < 4; j++) {
    const int n = n0 + wc * 64 + j * 16 + nn;
    const float bcv = bc[n];
#pragma unroll
    for (int i = 0; i < 4; i++) {
      const int prow = p0 + wr * 64 + i * 16 + mq;
#pragma unroll
      for (int rg = 0; rg < 4; rg++) {
        float v = acc[i][j][rg] + bcv;
        v = v > 0.f ? v : 0.f;
        Xc[(prow + rg) * 1280 + n] = f2bf(v);
      }
    }
  }
}

// ---------------- threefry2x32-20, key = (0, 42) ----------------
// Verified against Random123 KAT: key=(0,0), ctr=(0,0) -> (0x6b200159, 0x99ba4efe)
__device__ __forceinline__ void tf2x32(unsigned int x0, unsigned int x1,
                                       unsigned int& o0, unsigned int& o1) {
  const unsigned int ks1 = 42u;
  const unsigned int ks2 = 0x1BD11BDAu ^ 42u;   // ks0 = 0
  x1 += ks1;                                    // x0 += ks0 (0)
#define TF_RND(r) { x0 += x1; x1 = (x1 << (r)) | (x1 >> (32 - (r))); x1 ^= x0; }
  TF_RND(13) TF_RND(15) TF_RND(26) TF_RND(6)
  x0 += ks1; x1 += ks2 + 1u;
  TF_RND(17) TF_RND(29) TF_RND(16) TF_RND(24)
  x0 += ks2; x1 += 2u;
  TF_RND(13) TF_RND(15) TF_RND(26) TF_RND(6)
  x1 += ks1 + 3u;
  TF_RND(17) TF_RND(29) TF_RND(16) TF_RND(24)
  x0 += ks1; x1 += ks2 + 4u;
  TF_RND(13) TF_RND(15) TF_RND(26) TF_RND(6)
  x0 += ks2; x1 += 5u;
#undef TF_RND
  o0 = x0; o1 = x1;
}

// ---------------- kernel 3: mask counts (partitionable) + 3-head dot + atomics ----
// One block per pair p in [0,12288). S[p,c] = sum_d msb0( xor-fold(tf(0, d*PLANE + p*1280 + c)) )
__global__ __launch_bounds__(256) void mask_dot(
    const unsigned short* __restrict__ Xc,
    const float* __restrict__ W0, const float* __restrict__ W1,
    const float* __restrict__ W2, float* __restrict__ out)
{
  const int p = blockIdx.x;
  const int t = threadIdx.x;
  float s0 = 0.f, s1 = 0.f, s2 = 0.f;

  for (int qi = 0; qi < 5; qi++) {
    const int c = t + qi * 256;
    const unsigned int base = (unsigned int)(p * 1280 + c);
    int S = 0;
#pragma unroll
    for (unsigned int d = 0; d < 5; d++) {
      unsigned int o0, o1;
      tf2x32(0u, d * PLANE + base, o0, o1);   // counter = (hi,lo) of 64-bit flat idx; hi==0
      S += 1 - (int)((o0 ^ o1) >> 31);        // xor-fold, success = MSB==0
    }
    const float x = bf2f(Xc[base]);
    const float tx = x * (float)S;
    s0 += tx * W0[c]; s1 += tx * W1[c]; s2 += tx * W2[c];
  }

  // block reduction: wave shuffle then cross-wave via LDS
#pragma unroll
  for (int off = 32; off > 0; off >>= 1) {
    s0 += __shfl_xor(s0, off); s1 += __shfl_xor(s1, off); s2 += __shfl_xor(s2, off);
  }
  __shared__ float red[4][3];
  const int lane = t & 63, w = t >> 6;
  if (lane == 0) { red[w][0] = s0; red[w][1] = s1; red[w][2] = s2; }
  __syncthreads();
  if (t < 3) {
    const float s = red[0][t] + red[1][t] + red[2][t] + red[3][t];
    atomicAdd(&out[(p / 6) * 3 + t], s * (1.0f / 15.0f));
  }
}

extern "C" void kernel_launch(void* const* d_in, const int* in_sizes, int n_in,
                              void* d_out, int out_size, void* d_ws, size_t ws_size,
                              hipStream_t stream) {
  const float* x  = (const float*)d_in[0];
  // d_in[1] = ids2 (int32): repeat(arange(B),6) -> hardcoded p/6 mapping
  const float* Wc = (const float*)d_in[2];
  const float* bc = (const float*)d_in[3];
  const float* W0 = (const float*)d_in[4];
  const float* b0 = (const float*)d_in[5];
  const float* W1 = (const float*)d_in[6];
  const float* b1 = (const float*)d_in[7];
  const float* W2 = (const float*)d_in[8];
  const float* b2 = (const float*)d_in[9];
  float* out = (float*)d_out;

  char* ws = (char*)d_ws;
  unsigned short* xb = (unsigned short*)ws;                       // 20,971,520 B
  unsigned short* Wb = (unsigned short*)(ws + 20971520);          //  6,553,600 B
  unsigned short* Xc = (unsigned short*)(ws + 27525120);          // 31,457,280 B

  init_out<<<24, 256, 0, stream>>>(out, b0, b1, b2);
  conv_x<<<10240, 256, 0, stream>>>(x, xb);
  conv_w<<<12800, 256, 0, stream>>>(Wc, Wb);
  gemm_relu<<<960, 256, 0, stream>>>(xb, Wb, bc, Xc);
  mask_dot<<<12288, 256, 0, stream>>>(Xc, W0, W1, W2, out);
}

// Round 3
// 393.096 us; speedup vs baseline: 1.0329x; 1.0329x over previous
//
#include <hip/hip_runtime.h>

// Problem constants
// B=2048 patients, K=4, PAIRS=6 -> P=12288 pairs, C=1280, K_gemm=2560
// ii = [0,0,0,1,1,2], jj = [1,2,3,2,3,3]  (triu_indices(4,1))
// masks: jax threefry2x32 key(0,42), shape (5,12288,1280), PARTITIONABLE scheme:
//   bits[i] = o0 ^ o1, (o0,o1) = threefry2x32(key, (0, i)); success == MSB==0

typedef __attribute__((ext_vector_type(8))) short short8;
typedef __attribute__((ext_vector_type(4))) float f32x4;

#define PLANE 15728640u      // P*C
#define KS2   (0x1BD11BDAu ^ 42u)

__device__ __forceinline__ unsigned short f2bf(float f) {
  unsigned int u = __builtin_bit_cast(unsigned int, f);
  u = (u + 0x7FFFu + ((u >> 16) & 1u)) >> 16;   // RNE
  return (unsigned short)u;
}
__device__ __forceinline__ float bf2f(unsigned short h) {
  unsigned int u = ((unsigned int)h) << 16;
  return __builtin_bit_cast(float, u);
}

// ---------------- kernel 0: init output with biases ----------------
__global__ void init_out(float* __restrict__ out, const float* __restrict__ b0,
                         const float* __restrict__ b1, const float* __restrict__ b2) {
  int i = blockIdx.x * 256 + threadIdx.x;
  if (i < 2048 * 3) {
    int h = i % 3;
    out[i] = (h == 0) ? b0[0] : ((h == 1) ? b1[0] : b2[0]);
  }
}

// ---------------- kernel 1a: x fp32 -> bf16 ----------------
__global__ void conv_x(const float* __restrict__ x, unsigned short* __restrict__ xb) {
  int i = (blockIdx.x * 256 + threadIdx.x) * 4;
  float4 v = *(const float4*)(x + i);
  ushort4 o;
  o.x = f2bf(v.x); o.y = f2bf(v.y); o.z = f2bf(v.z); o.w = f2bf(v.w);
  *(ushort4*)(xb + i) = o;
}

// ---------------- kernel 1b: Wc (C,C,2) -> W' [1280][2560] bf16 ----------------
__global__ void conv_w(const float* __restrict__ Wc, unsigned short* __restrict__ Wb) {
  int idx = blockIdx.x * 256 + threadIdx.x;
  int n = idx / 2560;
  int k = idx - n * 2560;
  int side = (k >= 1280) ? 1 : 0;
  int cin = k - side * 1280;
  Wb[idx] = f2bf(Wc[n * 2560 + cin * 2 + side]);
}

// ---------------- kernel 2: GEMM  xc = relu(X' @ W'^T + bc), bf16 MFMA ----------
// M=12288, N=1280, K=2560. 128x128 tile, BK=32, 4 waves, 4x4 16x16 MFMA/wave.
// m97 structure: global_load_lds width=16, unpadded LDS rows of 64B (2-way
// conflict on ds_read_b128 is free per m136). K-loop split at side boundary.
#define GL_LDS(g, l) __builtin_amdgcn_global_load_lds( \
    (const __attribute__((address_space(1))) unsigned int*)(g), \
    (__attribute__((address_space(3))) unsigned int*)(l), 16, 0, 0)

__global__ __launch_bounds__(256) void gemm_relu(
    const unsigned short* __restrict__ Xb,   // [8192][1280] bf16
    const unsigned short* __restrict__ Wb,   // [1280][2560] bf16
    const float* __restrict__ bc,
    unsigned short* __restrict__ Xc)         // [12288][1280] bf16
{
  __shared__ unsigned short sA[128 * 32];    // unpadded: 64B rows (global_load_lds needs contiguity)
  __shared__ unsigned short sB[128 * 32];
  const int t = threadIdx.x;
  const int mblk = blockIdx.x % 96;
  const int nblk = blockIdx.x / 96;
  const int p0 = mblk * 128, n0 = nblk * 128;
  const int lane = t & 63, w = t >> 6;
  const int wr = w >> 1, wc = w & 1;
  const int q = lane & 3;                    // 16B chunk within row
  const int rl = lane >> 2;                  // row within 16-row issue group

  // staging rows: wave w stages A rows [w*32, w*32+32) and B rows likewise, 2 issues each
  int rA[2], rB[2], rN[2];
#pragma unroll
  for (int i = 0; i < 2; i++) {
    const int row = w * 32 + i * 16 + rl;
    const int pg = p0 + row;
    const int bA = pg / 6, pr = pg - bA * 6;
    rA[i] = bA * 4 + ((0x211000 >> (4 * pr)) & 7);   // ii side (k<1280)
    rB[i] = bA * 4 + ((0x332321 >> (4 * pr)) & 7);   // jj side (k>=1280)
    rN[i] = n0 + row;
  }
  // wave-uniform LDS bases (lane scatter = +lane*16B)
  unsigned short* ldsA0 = sA + (w * 32 + 0) * 32;
  unsigned short* ldsA1 = sA + (w * 32 + 16) * 32;
  unsigned short* ldsB0 = sB + (w * 32 + 0) * 32;
  unsigned short* ldsB1 = sB + (w * 32 + 16) * 32;
  // per-lane global base pointers
  const unsigned short* gA0s0 = Xb + rA[0] * 1280 + q * 8;
  const unsigned short* gA1s0 = Xb + rA[1] * 1280 + q * 8;
  const unsigned short* gA0s1 = Xb + rB[0] * 1280 + q * 8;
  const unsigned short* gA1s1 = Xb + rB[1] * 1280 + q * 8;
  const unsigned short* gB0 = Wb + rN[0] * 2560 + q * 8;
  const unsigned short* gB1 = Wb + rN[1] * 2560 + q * 8;

  f32x4 acc[4][4];
#pragma unroll
  for (int i = 0; i < 4; i++)
#pragma unroll
    for (int j = 0; j < 4; j++) acc[i][j] = (f32x4){0.f, 0.f, 0.f, 0.f};

  const int mrow = lane & 15;
  const int koff = (lane >> 4) * 8;

#define KSTEP(Ga0, Ga1, kb, kg)                                              \
  {                                                                          \
    __syncthreads();                                                         \
    GL_LDS(Ga0 + (kb), ldsA0);                                               \
    GL_LDS(Ga1 + (kb), ldsA1);                                               \
    GL_LDS(gB0 + (kg), ldsB0);                                               \
    GL_LDS(gB1 + (kg), ldsB1);                                               \
    __syncthreads();                                                         \
    short8 af[4], bfr[4];                                                    \
    _Pragma("unroll")                                                        \
    for (int i = 0; i < 4; i++)                                              \
      af[i] = *(const short8*)(sA + (wr * 64 + i * 16 + mrow) * 32 + koff);  \
    _Pragma("unroll")                                                        \
    for (int j = 0; j < 4; j++)                                              \
      bfr[j] = *(const short8*)(sB + (wc * 64 + j * 16 + mrow) * 32 + koff); \
    _Pragma("unroll")                                                        \
    for (int i = 0; i < 4; i++)                                              \
      _Pragma("unroll")                                                      \
      for (int j = 0; j < 4; j++)                                            \
        acc[i][j] = __builtin_amdgcn_mfma_f32_16x16x32_bf16(af[i], bfr[j],   \
                                                            acc[i][j], 0, 0, 0); \
  }

  for (int k0 = 0; k0 < 1280; k0 += 32) KSTEP(gA0s0, gA1s0, k0, k0);
  for (int k0 = 1280; k0 < 2560; k0 += 32) KSTEP(gA0s1, gA1s1, k0 - 1280, k0);
#undef KSTEP

  // epilogue: D layout col=lane&15, row=(lane>>4)*4+reg  [measured m89/m91]
  const int mq = (lane >> 4) * 4;
  const int nn = lane & 15;
#pragma unroll
  for (int j = 0; j < 4; j++) {
    const int n = n0 + wc * 64 + j * 16 + nn;
    const float bcv = bc[n];
#pragma unroll
    for (int i = 0; i < 4; i++) {
      const int prow = p0 + wr * 64 + i * 16 + mq;
#pragma unroll
      for (int rg = 0; rg < 4; rg++) {
        float v = acc[i][j][rg] + bcv;
        v = v > 0.f ? v : 0.f;
        Xc[(prow + rg) * 1280 + n] = f2bf(v);
      }
    }
  }
}

// ---------------- threefry2x32-20 MSB, key=(0,42), x0(counter hi)=0 ----------
// rotl via v_alignbit_b32 (1 inst); round-1 degenerate since x0 enters as 0.
__device__ __forceinline__ unsigned int rotl(unsigned int x, int r) {
  return __builtin_amdgcn_alignbit(x, x, 32 - r);
}
__device__ __forceinline__ unsigned int tf_msb(unsigned int x1) {
  // caller passes x1 = counter_lo + 42 (initial key add folded in)
  unsigned int x0 = x1;                 // round 1: x0 = 0 + x1
  x1 = rotl(x1, 13) ^ x0;
#define TF_R(r) { x0 += x1; x1 = rotl(x1, (r)) ^ x0; }
  TF_R(15) TF_R(26) TF_R(6)
  x0 += 42u; x1 += KS2 + 1u;
  TF_R(17) TF_R(29) TF_R(16) TF_R(24)
  x0 += KS2; x1 += 2u;
  TF_R(13) TF_R(15) TF_R(26) TF_R(6)
  x1 += 42u + 3u;
  TF_R(17) TF_R(29) TF_R(16) TF_R(24)
  x0 += 42u; x1 += KS2 + 4u;
  TF_R(13) TF_R(15) TF_R(26) TF_R(6)
  x0 += KS2; x1 += 5u;
#undef TF_R
  return (x0 ^ x1) >> 31;               // 1 == dropout-zero
}

// ---------------- kernel 3: mask counts + 3-head dot + segment atomics --------
__global__ __launch_bounds__(256) void mask_dot(
    const unsigned short* __restrict__ Xc,
    const float* __restrict__ W0, const float* __restrict__ W1,
    const float* __restrict__ W2, float* __restrict__ out)
{
  const int p = blockIdx.x;
  const int t = threadIdx.x;
  float s0 = 0.f, s1 = 0.f, s2 = 0.f;

  for (int qi = 0; qi < 5; qi++) {
    const int c = t + qi * 256;
    const unsigned int base = (unsigned int)(p * 1280 + c);
    // 5 independent cipher chains; d*PLANE+42 folds to one literal add each
    const unsigned int z = tf_msb(base + 42u)
                         + tf_msb(base + (PLANE + 42u))
                         + tf_msb(base + (2u * PLANE + 42u))
                         + tf_msb(base + (3u * PLANE + 42u))
                         + tf_msb(base + (4u * PLANE + 42u));
    const float S = (float)(5u - z);
    const float tx = bf2f(Xc[base]) * S;
    s0 += tx * W0[c]; s1 += tx * W1[c]; s2 += tx * W2[c];
  }

#pragma unroll
  for (int off = 32; off > 0; off >>= 1) {
    s0 += __shfl_xor(s0, off); s1 += __shfl_xor(s1, off); s2 += __shfl_xor(s2, off);
  }
  __shared__ float red[4][3];
  const int lane = t & 63, w = t >> 6;
  if (lane == 0) { red[w][0] = s0; red[w][1] = s1; red[w][2] = s2; }
  __syncthreads();
  if (t < 3) {
    const float s = red[0][t] + red[1][t] + red[2][t] + red[3][t];
    atomicAdd(&out[(p / 6) * 3 + t], s * (1.0f / 15.0f));
  }
}

extern "C" void kernel_launch(void* const* d_in, const int* in_sizes, int n_in,
                              void* d_out, int out_size, void* d_ws, size_t ws_size,
                              hipStream_t stream) {
  const float* x  = (const float*)d_in[0];
  // d_in[1] = ids2 (int32): repeat(arange(B),6) -> hardcoded p/6 mapping
  const float* Wc = (const float*)d_in[2];
  const float* bc = (const float*)d_in[3];
  const float* W0 = (const float*)d_in[4];
  const float* b0 = (const float*)d_in[5];
  const float* W1 = (const float*)d_in[6];
  const float* b1 = (const float*)d_in[7];
  const float* W2 = (const float*)d_in[8];
  const float* b2 = (const float*)d_in[9];
  float* out = (float*)d_out;

  char* ws = (char*)d_ws;
  unsigned short* xb = (unsigned short*)ws;                       // 20,971,520 B
  unsigned short* Wb = (unsigned short*)(ws + 20971520);          //  6,553,600 B
  unsigned short* Xc = (unsigned short*)(ws + 27525120);          // 31,457,280 B

  init_out<<<24, 256, 0, stream>>>(out, b0, b1, b2);
  conv_x<<<10240, 256, 0, stream>>>(x, xb);
  conv_w<<<12800, 256, 0, stream>>>(Wc, Wb);
  gemm_relu<<<960, 256, 0, stream>>>(xb, Wb, bc, Xc);
  mask_dot<<<12288, 256, 0, stream>>>(Xc, W0, W1, W2, out);
}

// Round 4
// 347.124 us; speedup vs baseline: 1.1697x; 1.1324x over previous
//
#include <hip/hip_runtime.h>

// B=2048 patients, K=4, PAIRS=6 -> P=12288 pairs, C=1280, K_gemm=2560
// ii = [0,0,0,1,1,2], jj = [1,2,3,2,3,3]
// masks: jax threefry2x32 key(0,42), (5,12288,1280), partitionable scheme:
//   bits[i] = o0^o1, (o0,o1) = tf2x32(key,(0,i)); dropout-keep == MSB==0

typedef __attribute__((ext_vector_type(8))) short short8;
typedef __attribute__((ext_vector_type(4))) float f32x4;

#define PLANE 15728640u      // P*C
#define KS2   (0x1BD11BDAu ^ 42u)

__device__ __forceinline__ unsigned short f2bf(float f) {
  unsigned int u = __builtin_bit_cast(unsigned int, f);
  u = (u + 0x7FFFu + ((u >> 16) & 1u)) >> 16;   // RNE
  return (unsigned short)u;
}
__device__ __forceinline__ float bf2f(unsigned short h) {
  unsigned int u = ((unsigned int)h) << 16;
  return __builtin_bit_cast(float, u);
}

// ---------------- kernel 0: init output with biases ----------------
__global__ void init_out(float* __restrict__ out, const float* __restrict__ b0,
                         const float* __restrict__ b1, const float* __restrict__ b2) {
  int i = blockIdx.x * 256 + threadIdx.x;
  if (i < 2048 * 3) {
    int h = i % 3;
    out[i] = (h == 0) ? b0[0] : ((h == 1) ? b1[0] : b2[0]);
  }
}

// ---------------- kernel 1a: x fp32 -> bf16 ----------------
__global__ void conv_x(const float* __restrict__ x, unsigned short* __restrict__ xb) {
  int i = (blockIdx.x * 256 + threadIdx.x) * 4;
  float4 v = *(const float4*)(x + i);
  ushort4 o;
  o.x = f2bf(v.x); o.y = f2bf(v.y); o.z = f2bf(v.z); o.w = f2bf(v.w);
  *(ushort4*)(xb + i) = o;
}

// ---------------- kernel 1b: Wc (C,C,2) -> W' [1280][2560] bf16 ----------------
__global__ void conv_w(const float* __restrict__ Wc, unsigned short* __restrict__ Wb) {
  int idx = blockIdx.x * 256 + threadIdx.x;
  int n = idx / 2560;
  int k = idx - n * 2560;
  int side = (k >= 1280) ? 1 : 0;
  int cin = k - side * 1280;
  Wb[idx] = f2bf(Wc[n * 2560 + cin * 2 + side]);
}

// ---------------- threefry2x32-20 MSB, key=(0,42), counter hi = 0 ----------
__device__ __forceinline__ unsigned int rotl(unsigned int x, int r) {
  return __builtin_amdgcn_alignbit(x, x, 32 - r);
}
__device__ __forceinline__ unsigned int tf_msb(unsigned int x1) {
  // caller passes x1 = counter_lo + 42 (initial key add folded in)
  unsigned int x0 = x1;                 // round 1: x0 = 0 + x1
  x1 = rotl(x1, 13) ^ x0;
#define TF_R(r) { x0 += x1; x1 = rotl(x1, (r)) ^ x0; }
  TF_R(15) TF_R(26) TF_R(6)
  x0 += 42u; x1 += KS2 + 1u;
  TF_R(17) TF_R(29) TF_R(16) TF_R(24)
  x0 += KS2; x1 += 2u;
  TF_R(13) TF_R(15) TF_R(26) TF_R(6)
  x1 += 42u + 3u;
  TF_R(17) TF_R(29) TF_R(16) TF_R(24)
  x0 += 42u; x1 += KS2 + 4u;
  TF_R(13) TF_R(15) TF_R(26) TF_R(6)
  x0 += KS2; x1 += 5u;
#undef TF_R
  return (x0 ^ x1) >> 31;               // 1 == dropout-zero
}

// ---------------- fused kernel: GEMM + relu + mask-RNG + 3-head dot + atomics ----
// Phase 1: m97-structure bf16 MFMA GEMM (128x128 tile, BK=32), acc->LDS tile (bf16).
// Phase 2: per-thread row-half, 5 threefry chains x c-unroll2 (ILP=10), head dots,
//          pair-shfl + per-row LDS sums + one atomic triple per patient-fragment.
#define GL_LDS(g, l) __builtin_amdgcn_global_load_lds( \
    (const __attribute__((address_space(1))) unsigned int*)(g), \
    (__attribute__((address_space(3))) unsigned int*)(l), 16, 0, 0)

__global__ __launch_bounds__(256) void gemm_relu_dot(
    const unsigned short* __restrict__ Xb,   // [8192][1280] bf16
    const unsigned short* __restrict__ Wb,   // [1280][2560] bf16
    const float* __restrict__ bc,
    const float* __restrict__ W0, const float* __restrict__ W1,
    const float* __restrict__ W2, float* __restrict__ out)
{
  __shared__ unsigned short sA[128 * 32];
  __shared__ unsigned short sB[128 * 32];
  __shared__ unsigned short tile[128 * 130];   // stride 130: phase-2 reads 2-way/free
  __shared__ float wts[3 * 128];
  __shared__ float rowsum[128 * 3];

  const int t = threadIdx.x;
  const int mblk = blockIdx.x % 96;
  const int nblk = blockIdx.x / 96;
  const int p0 = mblk * 128, n0 = nblk * 128;
  const int lane = t & 63, w = t >> 6;
  const int wr = w >> 1, wc = w & 1;
  const int q = lane & 3;
  const int rl = lane >> 2;

  if (t < 128) {                 // head weights for this n-range -> LDS
    wts[t]       = W0[n0 + t];
    wts[128 + t] = W1[n0 + t];
    wts[256 + t] = W2[n0 + t];
  }

  // staging rows: wave w stages A rows [w*32, w*32+32) and B rows likewise
  int rA[2], rB[2], rN[2];
#pragma unroll
  for (int i = 0; i < 2; i++) {
    const int row = w * 32 + i * 16 + rl;
    const int pg = p0 + row;
    const int bA = pg / 6, pr = pg - bA * 6;
    rA[i] = bA * 4 + ((0x211000 >> (4 * pr)) & 7);   // ii side (k<1280)
    rB[i] = bA * 4 + ((0x332321 >> (4 * pr)) & 7);   // jj side (k>=1280)
    rN[i] = n0 + row;
  }
  unsigned short* ldsA0 = sA + (w * 32 + 0) * 32;
  unsigned short* ldsA1 = sA + (w * 32 + 16) * 32;
  unsigned short* ldsB0 = sB + (w * 32 + 0) * 32;
  unsigned short* ldsB1 = sB + (w * 32 + 16) * 32;
  const unsigned short* gA0s0 = Xb + rA[0] * 1280 + q * 8;
  const unsigned short* gA1s0 = Xb + rA[1] * 1280 + q * 8;
  const unsigned short* gA0s1 = Xb + rB[0] * 1280 + q * 8;
  const unsigned short* gA1s1 = Xb + rB[1] * 1280 + q * 8;
  const unsigned short* gB0 = Wb + rN[0] * 2560 + q * 8;
  const unsigned short* gB1 = Wb + rN[1] * 2560 + q * 8;

  f32x4 acc[4][4];
#pragma unroll
  for (int i = 0; i < 4; i++)
#pragma unroll
    for (int j = 0; j < 4; j++) acc[i][j] = (f32x4){0.f, 0.f, 0.f, 0.f};

  const int mrow = lane & 15;
  const int koff = (lane >> 4) * 8;

#define KSTEP(Ga0, Ga1, kb, kg)                                              \
  {                                                                          \
    __syncthreads();                                                         \
    GL_LDS(Ga0 + (kb), ldsA0);                                               \
    GL_LDS(Ga1 + (kb), ldsA1);                                               \
    GL_LDS(gB0 + (kg), ldsB0);                                               \
    GL_LDS(gB1 + (kg), ldsB1);                                               \
    __syncthreads();                                                         \
    short8 af[4], bfr[4];                                                    \
    _Pragma("unroll")                                                        \
    for (int i = 0; i < 4; i++)                                              \
      af[i] = *(const short8*)(sA + (wr * 64 + i * 16 + mrow) * 32 + koff);  \
    _Pragma("unroll")                                                        \
    for (int j = 0; j < 4; j++)                                              \
      bfr[j] = *(const short8*)(sB + (wc * 64 + j * 16 + mrow) * 32 + koff); \
    _Pragma("unroll")                                                        \
    for (int i = 0; i < 4; i++)                                              \
      _Pragma("unroll")                                                      \
      for (int j = 0; j < 4; j++)                                            \
        acc[i][j] = __builtin_amdgcn_mfma_f32_16x16x32_bf16(af[i], bfr[j],   \
                                                            acc[i][j], 0, 0, 0); \
  }

  for (int k0 = 0; k0 < 1280; k0 += 32) KSTEP(gA0s0, gA1s0, k0, k0);
  for (int k0 = 1280; k0 < 2560; k0 += 32) KSTEP(gA0s1, gA1s1, k0 - 1280, k0);
#undef KSTEP

  // ---- phase 1 epilogue: v = relu(acc + bc) -> bf16 LDS tile ----
  // D layout: col=lane&15, row=(lane>>4)*4+reg [m89/m91]
  const int mq = (lane >> 4) * 4;
  const int nn = lane & 15;
#pragma unroll
  for (int j = 0; j < 4; j++) {
    const int ncol = wc * 64 + j * 16 + nn;
    const float bcv = bc[n0 + ncol];
#pragma unroll
    for (int i = 0; i < 4; i++) {
      const int rloc = wr * 64 + i * 16 + mq;
#pragma unroll
      for (int rg = 0; rg < 4; rg++) {
        float v = acc[i][j][rg] + bcv;
        v = v > 0.f ? v : 0.f;
        tile[(rloc + rg) * 130 + ncol] = f2bf(v);
      }
    }
  }
  __syncthreads();

  // ---- phase 2: threefry mask counts + 3-head dot ----
  const int r = t >> 1, h2 = t & 1;            // row 0..127, col-half 0/1
  const unsigned int cb =
      (unsigned int)(p0 + r) * 1280u + (unsigned int)(n0 + h2 * 64) + 42u;
  float s0 = 0.f, s1 = 0.f, s2 = 0.f;
#pragma unroll 2
  for (int c = 0; c < 64; ++c) {
    const unsigned int b = cb + (unsigned int)c;
    const unsigned int z = tf_msb(b)
                         + tf_msb(b + PLANE)
                         + tf_msb(b + 2u * PLANE)
                         + tf_msb(b + 3u * PLANE)
                         + tf_msb(b + 4u * PLANE);
    const float v = bf2f(tile[r * 130 + h2 * 64 + c]);
    const float tx = v * (float)(5u - z);
    const int wi = h2 * 64 + c;
    s0 += tx * wts[wi];
    s1 += tx * wts[128 + wi];
    s2 += tx * wts[256 + wi];
  }
  s0 += __shfl_xor(s0, 1);
  s1 += __shfl_xor(s1, 1);
  s2 += __shfl_xor(s2, 1);
  if (h2 == 0) {
    rowsum[r * 3 + 0] = s0; rowsum[r * 3 + 1] = s1; rowsum[r * 3 + 2] = s2;
  }
  __syncthreads();

  // ---- per-patient-fragment atomics (rows of one patient within this tile) ----
  if (t < 128) {
    const int pr = p0 + t;
    const int rem = pr % 6;
    if (t == 0 || rem == 0) {
      int nrows = 6 - rem;
      if (nrows > 128 - t) nrows = 128 - t;
      float a0 = 0.f, a1 = 0.f, a2 = 0.f;
      for (int k2 = 0; k2 < nrows; k2++) {
        a0 += rowsum[(t + k2) * 3 + 0];
        a1 += rowsum[(t + k2) * 3 + 1];
        a2 += rowsum[(t + k2) * 3 + 2];
      }
      const int pat = pr / 6;
      atomicAdd(&out[pat * 3 + 0], a0 * (1.0f / 15.0f));
      atomicAdd(&out[pat * 3 + 1], a1 * (1.0f / 15.0f));
      atomicAdd(&out[pat * 3 + 2], a2 * (1.0f / 15.0f));
    }
  }
}

extern "C" void kernel_launch(void* const* d_in, const int* in_sizes, int n_in,
                              void* d_out, int out_size, void* d_ws, size_t ws_size,
                              hipStream_t stream) {
  const float* x  = (const float*)d_in[0];
  // d_in[1] = ids2 (int32): repeat(arange(B),6) -> hardcoded p/6 mapping
  const float* Wc = (const float*)d_in[2];
  const float* bc = (const float*)d_in[3];
  const float* W0 = (const float*)d_in[4];
  const float* b0 = (const float*)d_in[5];
  const float* W1 = (const float*)d_in[6];
  const float* b1 = (const float*)d_in[7];
  const float* W2 = (const float*)d_in[8];
  const float* b2 = (const float*)d_in[9];
  float* out = (float*)d_out;

  char* ws = (char*)d_ws;
  unsigned short* xb = (unsigned short*)ws;                       // 20,971,520 B
  unsigned short* Wb = (unsigned short*)(ws + 20971520);          //  6,553,600 B

  init_out<<<24, 256, 0, stream>>>(out, b0, b1, b2);
  conv_x<<<10240, 256, 0, stream>>>(x, xb);
  conv_w<<<12800, 256, 0, stream>>>(Wc, Wb);
  gemm_relu_dot<<<960, 256, 0, stream>>>(xb, Wb, bc, W0, W1, W2, out);
}

// Round 5
// 315.902 us; speedup vs baseline: 1.2853x; 1.0988x over previous
//
#include <hip/hip_runtime.h>

// B=2048 patients, K=4, PAIRS=6 -> P=12288 pairs, C=1280, K_gemm=2560
// ii = [0,0,0,1,1,2], jj = [1,2,3,2,3,3]
// masks: jax threefry2x32 key(0,42), (5,12288,1280), partitionable scheme:
//   bits[i] = o0^o1, (o0,o1) = tf2x32(key,(0,i)); dropout-keep == MSB==0

typedef __attribute__((ext_vector_type(8))) short short8;
typedef __attribute__((ext_vector_type(4))) float f32x4;

#define PLANE 15728640u      // P*C
#define KS2   (0x1BD11BDAu ^ 42u)

__device__ __forceinline__ unsigned short f2bf(float f) {
  unsigned int u = __builtin_bit_cast(unsigned int, f);
  u = (u + 0x7FFFu + ((u >> 16) & 1u)) >> 16;   // RNE
  return (unsigned short)u;
}
__device__ __forceinline__ float bf2f(unsigned short h) {
  unsigned int u = ((unsigned int)h) << 16;
  return __builtin_bit_cast(float, u);
}

// ---------------- kernel 0: init output with biases ----------------
__global__ void init_out(float* __restrict__ out, const float* __restrict__ b0,
                         const float* __restrict__ b1, const float* __restrict__ b2) {
  int i = blockIdx.x * 256 + threadIdx.x;
  if (i < 2048 * 3) {
    int h = i % 3;
    out[i] = (h == 0) ? b0[0] : ((h == 1) ? b1[0] : b2[0]);
  }
}

// ---------------- kernel 1a: x fp32 -> bf16 ----------------
__global__ void conv_x(const float* __restrict__ x, unsigned short* __restrict__ xb) {
  int i = (blockIdx.x * 256 + threadIdx.x) * 4;
  float4 v = *(const float4*)(x + i);
  ushort4 o;
  o.x = f2bf(v.x); o.y = f2bf(v.y); o.z = f2bf(v.z); o.w = f2bf(v.w);
  *(ushort4*)(xb + i) = o;
}

// ---------------- kernel 1b: Wc (C,C,2) -> W' [1280][2560] bf16 ----------------
__global__ void conv_w(const float* __restrict__ Wc, unsigned short* __restrict__ Wb) {
  int idx = blockIdx.x * 256 + threadIdx.x;
  int n = idx / 2560;
  int k = idx - n * 2560;
  int side = (k >= 1280) ? 1 : 0;
  int cin = k - side * 1280;
  Wb[idx] = f2bf(Wc[n * 2560 + cin * 2 + side]);
}

// ---------------- threefry2x32-20 MSB, key=(0,42), counter hi = 0 ----------
__device__ __forceinline__ unsigned int rotl(unsigned int x, int r) {
  return __builtin_amdgcn_alignbit(x, x, 32 - r);
}
__device__ __forceinline__ unsigned int tf_msb(unsigned int x1) {
  // caller passes x1 = counter_lo + 42 (initial key add folded in)
  unsigned int x0 = x1;                 // round 1: x0 = 0 + x1
  x1 = rotl(x1, 13) ^ x0;
#define TF_R(r) { x0 += x1; x1 = rotl(x1, (r)) ^ x0; }
  TF_R(15) TF_R(26) TF_R(6)
  x0 += 42u; x1 += KS2 + 1u;
  TF_R(17) TF_R(29) TF_R(16) TF_R(24)
  x0 += KS2; x1 += 2u;
  TF_R(13) TF_R(15) TF_R(26) TF_R(6)
  x1 += 42u + 3u;
  TF_R(17) TF_R(29) TF_R(16) TF_R(24)
  x0 += 42u; x1 += KS2 + 4u;
  TF_R(13) TF_R(15) TF_R(26) TF_R(6)
  x0 += KS2; x1 += 5u;
#undef TF_R
  return (x0 ^ x1) >> 31;               // 1 == dropout-zero
}

// ---------------- fused kernel: GEMM(+relu) with in-loop mask RNG + head dot ----
// RNG cells per thread == its MFMA accumulator cells -> no LDS tile round-trip.
// 1 cell (5 tf_msb evals) per K-iter for iters 0..63; nibble-packed into zLDS.
#define GL_LDS(g, l) __builtin_amdgcn_global_load_lds( \
    (const __attribute__((address_space(1))) unsigned int*)(g), \
    (__attribute__((address_space(3))) unsigned int*)(l), 16, 0, 0)

__global__ __launch_bounds__(256) void gemm_relu_dot(
    const unsigned short* __restrict__ Xb,   // [8192][1280] bf16
    const unsigned short* __restrict__ Wb,   // [1280][2560] bf16
    const float* __restrict__ bc,
    const float* __restrict__ W0, const float* __restrict__ W1,
    const float* __restrict__ W2, float* __restrict__ out)
{
  __shared__ unsigned short sA[128 * 32];
  __shared__ unsigned short sB[128 * 32];
  __shared__ unsigned int zLDS[8 * 256];       // [chunk][thread], conflict-free
  __shared__ float rowsumA[128 * 3];           // wc=0 half
  __shared__ float rowsumB[128 * 3];           // wc=1 half

  const int t = threadIdx.x;
  const int mblk = blockIdx.x % 96;
  const int nblk = blockIdx.x / 96;
  const int p0 = mblk * 128, n0 = nblk * 128;
  const int lane = t & 63, w = t >> 6;
  const int wr = w >> 1, wc = w & 1;
  const int q = lane & 3;
  const int rl = lane >> 2;
  const int mrow = lane & 15;
  const int koff = (lane >> 4) * 8;
  const int mq = (lane >> 4) * 4;              // C/D row quad [m89/m91]
  const int nn = lane & 15;                    // C/D col

  // staging rows: wave w stages A rows [w*32, w*32+32) and B rows likewise
  int rA[2], rB[2], rN[2];
#pragma unroll
  for (int i = 0; i < 2; i++) {
    const int row = w * 32 + i * 16 + rl;
    const int pg = p0 + row;
    const int bA = pg / 6, pr = pg - bA * 6;
    rA[i] = bA * 4 + ((0x211000 >> (4 * pr)) & 7);   // ii side (k<1280)
    rB[i] = bA * 4 + ((0x332321 >> (4 * pr)) & 7);   // jj side (k>=1280)
    rN[i] = n0 + row;
  }
  unsigned short* ldsA0 = sA + (w * 32 + 0) * 32;
  unsigned short* ldsA1 = sA + (w * 32 + 16) * 32;
  unsigned short* ldsB0 = sB + (w * 32 + 0) * 32;
  unsigned short* ldsB1 = sB + (w * 32 + 16) * 32;
  const unsigned short* gA0s0 = Xb + rA[0] * 1280 + q * 8;
  const unsigned short* gA1s0 = Xb + rA[1] * 1280 + q * 8;
  const unsigned short* gA0s1 = Xb + rB[0] * 1280 + q * 8;
  const unsigned short* gA1s1 = Xb + rB[1] * 1280 + q * 8;
  const unsigned short* gB0 = Wb + rN[0] * 2560 + q * 8;
  const unsigned short* gB1 = Wb + rN[1] * 2560 + q * 8;

  f32x4 acc[4][4];
#pragma unroll
  for (int i = 0; i < 4; i++)
#pragma unroll
    for (int j = 0; j < 4; j++) acc[i][j] = (f32x4){0.f, 0.f, 0.f, 0.f};

  // RNG base for this thread's accumulator cells:
  // cell idx (0..63): i=idx>>4, j=(idx>>2)&3, rg=idx&3
  // counter = (p0+wr*64+i*16+mq+rg)*1280 + n0+wc*64+j*16+nn + 42
  const unsigned int tb =
      (unsigned int)((p0 + wr * 64 + mq) * 1280 + n0 + wc * 64 + nn) + 42u;

#define KSTEP(Ga0, Ga1, kb, kg)                                              \
  {                                                                          \
    __syncthreads();                                                         \
    GL_LDS(Ga0 + (kb), ldsA0);                                               \
    GL_LDS(Ga1 + (kb), ldsA1);                                               \
    GL_LDS(gB0 + (kg), ldsB0);                                               \
    GL_LDS(gB1 + (kg), ldsB1);                                               \
    __syncthreads();                                                         \
    short8 af[4], bfr[4];                                                    \
    _Pragma("unroll")                                                        \
    for (int i = 0; i < 4; i++)                                              \
      af[i] = *(const short8*)(sA + (wr * 64 + i * 16 + mrow) * 32 + koff);  \
    _Pragma("unroll")                                                        \
    for (int j = 0; j < 4; j++)                                              \
      bfr[j] = *(const short8*)(sB + (wc * 64 + j * 16 + mrow) * 32 + koff); \
    _Pragma("unroll")                                                        \
    for (int i = 0; i < 4; i++)                                              \
      _Pragma("unroll")                                                      \
      for (int j = 0; j < 4; j++)                                            \
        acc[i][j] = __builtin_amdgcn_mfma_f32_16x16x32_bf16(af[i], bfr[j],   \
                                                            acc[i][j], 0, 0, 0); \
  }

#define CELL_RNG(it)                                                         \
  {                                                                          \
    const int idx = (it);                                                    \
    const unsigned int b = tb +                                              \
        (unsigned int)((((idx >> 4) * 16 + (idx & 3)) * 1280) +              \
                       (((idx >> 2) & 3) * 16));                             \
    const unsigned int z5 = tf_msb(b) + tf_msb(b + PLANE) +                  \
                            tf_msb(b + 2u * PLANE) + tf_msb(b + 3u * PLANE) +\
                            tf_msb(b + 4u * PLANE);                          \
    zacc |= z5 << (4 * sub);                                                 \
  }

  // chunks 0..4: side0 K-steps + cells 0..39
  for (int c8 = 0; c8 < 5; c8++) {
    unsigned int zacc = 0;
    for (int sub = 0; sub < 8; sub++) {
      const int it = c8 * 8 + sub;
      KSTEP(gA0s0, gA1s0, it * 32, it * 32);
      CELL_RNG(it);
    }
    zLDS[c8 * 256 + t] = zacc;
  }
  // chunks 5..7: side1 K-steps + cells 40..63
  for (int c8 = 5; c8 < 8; c8++) {
    unsigned int zacc = 0;
    for (int sub = 0; sub < 8; sub++) {
      const int it = c8 * 8 + sub;
      KSTEP(gA0s1, gA1s1, (it - 40) * 32, it * 32);
      CELL_RNG(it);
    }
    zLDS[c8 * 256 + t] = zacc;
  }
  // chunks 8..9: side1 K-steps only
  for (int c8 = 8; c8 < 10; c8++) {
    for (int sub = 0; sub < 8; sub++) {
      const int it = c8 * 8 + sub;
      KSTEP(gA0s1, gA1s1, (it - 40) * 32, it * 32);
    }
  }
#undef KSTEP
#undef CELL_RNG

  // ---- epilogue: relu+bias, apply mask counts, 3-head dot, row reduction ----
  unsigned int zq[8];
#pragma unroll
  for (int c = 0; c < 8; c++) zq[c] = zLDS[c * 256 + t];

  float w0v[4], w1v[4], w2v[4], bcv[4];
#pragma unroll
  for (int j = 0; j < 4; j++) {
    const int n = n0 + wc * 64 + j * 16 + nn;
    w0v[j] = W0[n]; w1v[j] = W1[n]; w2v[j] = W2[n]; bcv[j] = bc[n];
  }

  float* const dst = (wc == 0) ? rowsumA : rowsumB;
#pragma unroll
  for (int i = 0; i < 4; i++) {
#pragma unroll
    for (int rg = 0; rg < 4; rg++) {
      float s0 = 0.f, s1 = 0.f, s2 = 0.f;
#pragma unroll
      for (int j = 0; j < 4; j++) {
        const int idx = i * 16 + j * 4 + rg;
        const unsigned int z5 = (zq[idx >> 3] >> (4 * (idx & 7))) & 7u;
        float v = acc[i][j][rg] + bcv[j];
        v = v > 0.f ? v : 0.f;
        const float tx = v * (float)(5 - (int)z5);
        s0 += tx * w0v[j]; s1 += tx * w1v[j]; s2 += tx * w2v[j];
      }
      // 16-lane (nn) reduction within the mq-group: lanes share row
#pragma unroll
      for (int off = 1; off < 16; off <<= 1) {
        s0 += __shfl_xor(s0, off);
        s1 += __shfl_xor(s1, off);
        s2 += __shfl_xor(s2, off);
      }
      if (nn == 0) {
        const int row = wr * 64 + i * 16 + mq + rg;
        dst[row * 3 + 0] = s0; dst[row * 3 + 1] = s1; dst[row * 3 + 2] = s2;
      }
    }
  }
  __syncthreads();

  // ---- per-patient-fragment atomics ----
  if (t < 128) {
    const int pr = p0 + t;
    const int rem = pr % 6;
    if (t == 0 || rem == 0) {
      int nrows = 6 - rem;
      if (nrows > 128 - t) nrows = 128 - t;
      float a0 = 0.f, a1 = 0.f, a2 = 0.f;
      for (int k2 = 0; k2 < nrows; k2++) {
        a0 += rowsumA[(t + k2) * 3 + 0] + rowsumB[(t + k2) * 3 + 0];
        a1 += rowsumA[(t + k2) * 3 + 1] + rowsumB[(t + k2) * 3 + 1];
        a2 += rowsumA[(t + k2) * 3 + 2] + rowsumB[(t + k2) * 3 + 2];
      }
      const int pat = pr / 6;
      atomicAdd(&out[pat * 3 + 0], a0 * (1.0f / 15.0f));
      atomicAdd(&out[pat * 3 + 1], a1 * (1.0f / 15.0f));
      atomicAdd(&out[pat * 3 + 2], a2 * (1.0f / 15.0f));
    }
  }
}

extern "C" void kernel_launch(void* const* d_in, const int* in_sizes, int n_in,
                              void* d_out, int out_size, void* d_ws, size_t ws_size,
                              hipStream_t stream) {
  const float* x  = (const float*)d_in[0];
  // d_in[1] = ids2 (int32): repeat(arange(B),6) -> hardcoded p/6 mapping
  const float* Wc = (const float*)d_in[2];
  const float* bc = (const float*)d_in[3];
  const float* W0 = (const float*)d_in[4];
  const float* b0 = (const float*)d_in[5];
  const float* W1 = (const float*)d_in[6];
  const float* b1 = (const float*)d_in[7];
  const float* W2 = (const float*)d_in[8];
  const float* b2 = (const float*)d_in[9];
  float* out = (float*)d_out;

  char* ws = (char*)d_ws;
  unsigned short* xb = (unsigned short*)ws;                       // 20,971,520 B
  unsigned short* Wb = (unsigned short*)(ws + 20971520);          //  6,553,600 B

  init_out<<<24, 256, 0, stream>>>(out, b0, b1, b2);
  conv_x<<<10240, 256, 0, stream>>>(x, xb);
  conv_w<<<12800, 256, 0, stream>>>(Wc, Wb);
  gemm_relu_dot<<<960, 256, 0, stream>>>(xb, Wb, bc, W0, W1, W2, out);
}

// Round 6
// 314.165 us; speedup vs baseline: 1.2924x; 1.0055x over previous
//
#include <hip/hip_runtime.h>

// B=2048 patients, K=4, PAIRS=6 -> P=12288 pairs, C=1280, K_gemm=2560
// ii = [0,0,0,1,1,2], jj = [1,2,3,2,3,3]
// masks: jax threefry2x32 key(0,42), (5,12288,1280), partitionable scheme:
//   bits[i] = o0^o1, (o0,o1) = tf2x32(key,(0,i)); dropout-keep == MSB==0

typedef __attribute__((ext_vector_type(8))) short short8;
typedef __attribute__((ext_vector_type(4))) float f32x4;

#define PLANE 15728640u      // P*C
#define KS2   (0x1BD11BDAu ^ 42u)

__device__ __forceinline__ unsigned short f2bf(float f) {
  unsigned int u = __builtin_bit_cast(unsigned int, f);
  u = (u + 0x7FFFu + ((u >> 16) & 1u)) >> 16;   // RNE
  return (unsigned short)u;
}
__device__ __forceinline__ float bf2f(unsigned short h) {
  unsigned int u = ((unsigned int)h) << 16;
  return __builtin_bit_cast(float, u);
}

// ---------------- prep kernel: conv_x + conv_w + init_out in one dispatch ------
__global__ __launch_bounds__(256) void prep(
    const float* __restrict__ x, unsigned short* __restrict__ xb,
    const float* __restrict__ Wc, unsigned short* __restrict__ Wb,
    const float* __restrict__ b0, const float* __restrict__ b1,
    const float* __restrict__ b2, float* __restrict__ out) {
  const int bid = blockIdx.x;
  const int t = threadIdx.x;
  if (bid < 10240) {                      // x fp32 -> bf16 (4 elems/thread)
    const int i = (bid * 256 + t) * 4;
    float4 v = *(const float4*)(x + i);
    ushort4 o;
    o.x = f2bf(v.x); o.y = f2bf(v.y); o.z = f2bf(v.z); o.w = f2bf(v.w);
    *(ushort4*)(xb + i) = o;
  } else if (bid < 23040) {               // Wc (C,C,2) -> W' [1280][2560] bf16
    const int idx = (bid - 10240) * 256 + t;
    const int n = idx / 2560;
    const int k = idx - n * 2560;
    const int side = (k >= 1280) ? 1 : 0;
    const int cin = k - side * 1280;
    Wb[idx] = f2bf(Wc[n * 2560 + cin * 2 + side]);
  } else {                                // out[b][h] = bias_h
    const int i = (bid - 23040) * 256 + t;
    if (i < 2048 * 3) {
      const int h = i % 3;
      out[i] = (h == 0) ? b0[0] : ((h == 1) ? b1[0] : b2[0]);
    }
  }
}

// ---------------- threefry2x32-20 MSB, key=(0,42), counter hi = 0 ----------
__device__ __forceinline__ unsigned int rotl(unsigned int x, int r) {
  return __builtin_amdgcn_alignbit(x, x, 32 - r);
}
__device__ __forceinline__ unsigned int tf_msb(unsigned int x1) {
  // caller passes x1 = counter_lo + 42 (initial key add folded in)
  unsigned int x0 = x1;                 // round 1: x0 = 0 + x1
  x1 = rotl(x1, 13) ^ x0;
#define TF_R(r) { x0 += x1; x1 = rotl(x1, (r)) ^ x0; }
  TF_R(15) TF_R(26) TF_R(6)
  x0 += 42u; x1 += KS2 + 1u;
  TF_R(17) TF_R(29) TF_R(16) TF_R(24)
  x0 += KS2; x1 += 2u;
  TF_R(13) TF_R(15) TF_R(26) TF_R(6)
  x1 += 42u + 3u;
  TF_R(17) TF_R(29) TF_R(16) TF_R(24)
  x0 += 42u; x1 += KS2 + 4u;
  TF_R(13) TF_R(15) TF_R(26) TF_R(6)
  x0 += KS2; x1 += 5u;
#undef TF_R
  return (x0 ^ x1) >> 31;               // 1 == dropout-zero
}

// ---------------- fused kernel: dbuf GEMM(+relu) + in-loop mask RNG + head dot ----
// Double-buffered staging: ONE barrier per K-step, vmcnt drain hidden behind
// the ~800-cyc MFMA+RNG compute (loads for it+1 issued right after ds_reads).
#define GL_LDS(g, l) __builtin_amdgcn_global_load_lds( \
    (const __attribute__((address_space(1))) unsigned int*)(g), \
    (__attribute__((address_space(3))) unsigned int*)(l), 16, 0, 0)

__global__ __launch_bounds__(256) void gemm_relu_dot(
    const unsigned short* __restrict__ Xb,   // [8192][1280] bf16
    const unsigned short* __restrict__ Wb,   // [1280][2560] bf16
    const float* __restrict__ bc,
    const float* __restrict__ W0, const float* __restrict__ W1,
    const float* __restrict__ W2, float* __restrict__ out)
{
  __shared__ unsigned short sA[2 * 128 * 32];  // double-buffered (8 KB per buf)
  __shared__ unsigned short sB[2 * 128 * 32];
  __shared__ unsigned int zLDS[8 * 256];       // [chunk][thread], conflict-free
  __shared__ float rowsumA[128 * 3];           // wc=0 half
  __shared__ float rowsumB[128 * 3];           // wc=1 half

  const int t = threadIdx.x;
  const int mblk = blockIdx.x % 96;
  const int nblk = blockIdx.x / 96;
  const int p0 = mblk * 128, n0 = nblk * 128;
  const int lane = t & 63, w = t >> 6;
  const int wr = w >> 1, wc = w & 1;
  const int q = lane & 3;
  const int rl = lane >> 2;
  const int mrow = lane & 15;
  const int koff = (lane >> 4) * 8;
  const int mq = (lane >> 4) * 4;              // C/D row quad [m89/m91]
  const int nn = lane & 15;                    // C/D col

  // staging rows: wave w stages A rows [w*32, w*32+32) and B rows likewise
  int rA[2], rB[2], rN[2];
#pragma unroll
  for (int i = 0; i < 2; i++) {
    const int row = w * 32 + i * 16 + rl;
    const int pg = p0 + row;
    const int bA = pg / 6, pr = pg - bA * 6;
    rA[i] = bA * 4 + ((0x211000 >> (4 * pr)) & 7);   // ii side (k<1280)
    rB[i] = bA * 4 + ((0x332321 >> (4 * pr)) & 7);   // jj side (k>=1280)
    rN[i] = n0 + row;
  }
  unsigned short* const ldsA0 = sA + (w * 32 + 0) * 32;
  unsigned short* const ldsA1 = sA + (w * 32 + 16) * 32;
  unsigned short* const ldsB0 = sB + (w * 32 + 0) * 32;
  unsigned short* const ldsB1 = sB + (w * 32 + 16) * 32;
  const unsigned short* const gA0s0 = Xb + rA[0] * 1280 + q * 8;
  const unsigned short* const gA1s0 = Xb + rA[1] * 1280 + q * 8;
  const unsigned short* const gA0s1 = Xb + rB[0] * 1280 + q * 8;
  const unsigned short* const gA1s1 = Xb + rB[1] * 1280 + q * 8;
  const unsigned short* const gB0 = Wb + rN[0] * 2560 + q * 8;
  const unsigned short* const gB1 = Wb + rN[1] * 2560 + q * 8;

  f32x4 acc[4][4];
#pragma unroll
  for (int i = 0; i < 4; i++)
#pragma unroll
    for (int j = 0; j < 4; j++) acc[i][j] = (f32x4){0.f, 0.f, 0.f, 0.f};

  // RNG base: cell idx (0..63): i=idx>>4, j=(idx>>2)&3, rg=idx&3
  // counter = (p0+wr*64+i*16+mq+rg)*1280 + n0+wc*64+j*16+nn + 42
  const unsigned int tb =
      (unsigned int)((p0 + wr * 64 + mq) * 1280 + n0 + wc * 64 + nn) + 42u;

  // prefetch for iteration `nxt` into buffer bb (0/1)
#define PF(nxt, bb)                                                          \
  {                                                                          \
    const int _n = (nxt);                                                    \
    if (_n < 80) {                                                           \
      const int _s1 = (_n >= 40);                                            \
      const unsigned short* _a0 = _s1 ? gA0s1 : gA0s0;                       \
      const unsigned short* _a1 = _s1 ? gA1s1 : gA1s0;                       \
      const int _kb = (_s1 ? (_n - 40) : _n) * 32;                           \
      const int _kg = _n * 32;                                               \
      GL_LDS(_a0 + _kb, ldsA0 + (bb) * 4096);                                \
      GL_LDS(_a1 + _kb, ldsA1 + (bb) * 4096);                                \
      GL_LDS(gB0 + _kg, ldsB0 + (bb) * 4096);                                \
      GL_LDS(gB1 + _kg, ldsB1 + (bb) * 4096);                                \
    }                                                                        \
  }

  // one K-step: barrier -> ds_read(cur buf) -> prefetch next -> 16 MFMA
#define KSTEP(it, bb)                                                        \
  {                                                                          \
    __syncthreads();                                                         \
    short8 af[4], bfr[4];                                                    \
    _Pragma("unroll")                                                        \
    for (int i = 0; i < 4; i++)                                              \
      af[i] = *(const short8*)(sA + (bb) * 4096 +                            \
                               (wr * 64 + i * 16 + mrow) * 32 + koff);       \
    _Pragma("unroll")                                                        \
    for (int j = 0; j < 4; j++)                                              \
      bfr[j] = *(const short8*)(sB + (bb) * 4096 +                           \
                                (wc * 64 + j * 16 + mrow) * 32 + koff);      \
    PF((it) + 1, ((bb) ^ 1));                                                \
    _Pragma("unroll")                                                        \
    for (int i = 0; i < 4; i++)                                              \
      _Pragma("unroll")                                                      \
      for (int j = 0; j < 4; j++)                                            \
        acc[i][j] = __builtin_amdgcn_mfma_f32_16x16x32_bf16(af[i], bfr[j],   \
                                                            acc[i][j], 0, 0, 0); \
  }

#define CELL_RNG(it)                                                         \
  {                                                                          \
    const int idx = (it);                                                    \
    const unsigned int b = tb +                                              \
        (unsigned int)((((idx >> 4) * 16 + (idx & 3)) * 1280) +              \
                       (((idx >> 2) & 3) * 16));                             \
    const unsigned int z5 = tf_msb(b) + tf_msb(b + PLANE) +                  \
                            tf_msb(b + 2u * PLANE) + tf_msb(b + 3u * PLANE) +\
                            tf_msb(b + 4u * PLANE);                          \
    zacc |= z5 << (4 * sub);                                                 \
  }

  PF(0, 0);                                    // prologue: first tile

  // chunks 0..7: K-steps with one RNG cell each (cells 0..63)
  for (int c8 = 0; c8 < 8; c8++) {
    unsigned int zacc = 0;
#pragma unroll
    for (int sub = 0; sub < 8; sub++) {
      const int it = c8 * 8 + sub;
      KSTEP(it, (sub & 1));                    // it&1 == sub&1 (chunks are even)
      CELL_RNG(it);
    }
    zLDS[c8 * 256 + t] = zacc;
  }
  // chunks 8..9: K-steps only
  for (int c8 = 8; c8 < 10; c8++) {
#pragma unroll
    for (int sub = 0; sub < 8; sub++) {
      const int it = c8 * 8 + sub;
      KSTEP(it, (sub & 1));
    }
  }
#undef KSTEP
#undef PF
#undef CELL_RNG

  // ---- epilogue: relu+bias, apply mask counts, 3-head dot, row reduction ----
  unsigned int zq[8];
#pragma unroll
  for (int c = 0; c < 8; c++) zq[c] = zLDS[c * 256 + t];

  float w0v[4], w1v[4], w2v[4], bcv[4];
#pragma unroll
  for (int j = 0; j < 4; j++) {
    const int n = n0 + wc * 64 + j * 16 + nn;
    w0v[j] = W0[n]; w1v[j] = W1[n]; w2v[j] = W2[n]; bcv[j] = bc[n];
  }

  float* const dst = (wc == 0) ? rowsumA : rowsumB;
#pragma unroll
  for (int i = 0; i < 4; i++) {
#pragma unroll
    for (int rg = 0; rg < 4; rg++) {
      float s0 = 0.f, s1 = 0.f, s2 = 0.f;
#pragma unroll
      for (int j = 0; j < 4; j++) {
        const int idx = i * 16 + j * 4 + rg;
        const unsigned int z5 = (zq[idx >> 3] >> (4 * (idx & 7))) & 7u;
        float v = acc[i][j][rg] + bcv[j];
        v = v > 0.f ? v : 0.f;
        const float tx = v * (float)(5 - (int)z5);
        s0 += tx * w0v[j]; s1 += tx * w1v[j]; s2 += tx * w2v[j];
      }
      // 16-lane (nn) reduction: lanes share the output row
#pragma unroll
      for (int off = 1; off < 16; off <<= 1) {
        s0 += __shfl_xor(s0, off);
        s1 += __shfl_xor(s1, off);
        s2 += __shfl_xor(s2, off);
      }
      if (nn == 0) {
        const int row = wr * 64 + i * 16 + mq + rg;
        dst[row * 3 + 0] = s0; dst[row * 3 + 1] = s1; dst[row * 3 + 2] = s2;
      }
    }
  }
  __syncthreads();

  // ---- per-patient-fragment atomics ----
  if (t < 128) {
    const int pr = p0 + t;
    const int rem = pr % 6;
    if (t == 0 || rem == 0) {
      int nrows = 6 - rem;
      if (nrows > 128 - t) nrows = 128 - t;
      float a0 = 0.f, a1 = 0.f, a2 = 0.f;
      for (int k2 = 0; k2 < nrows; k2++) {
        a0 += rowsumA[(t + k2) * 3 + 0] + rowsumB[(t + k2) * 3 + 0];
        a1 += rowsumA[(t + k2) * 3 + 1] + rowsumB[(t + k2) * 3 + 1];
        a2 += rowsumA[(t + k2) * 3 + 2] + rowsumB[(t + k2) * 3 + 2];
      }
      const int pat = pr / 6;
      atomicAdd(&out[pat * 3 + 0], a0 * (1.0f / 15.0f));
      atomicAdd(&out[pat * 3 + 1], a1 * (1.0f / 15.0f));
      atomicAdd(&out[pat * 3 + 2], a2 * (1.0f / 15.0f));
    }
  }
}

extern "C" void kernel_launch(void* const* d_in, const int* in_sizes, int n_in,
                              void* d_out, int out_size, void* d_ws, size_t ws_size,
                              hipStream_t stream) {
  const float* x  = (const float*)d_in[0];
  // d_in[1] = ids2 (int32): repeat(arange(B),6) -> hardcoded p/6 mapping
  const float* Wc = (const float*)d_in[2];
  const float* bc = (const float*)d_in[3];
  const float* W0 = (const float*)d_in[4];
  const float* b0 = (const float*)d_in[5];
  const float* W1 = (const float*)d_in[6];
  const float* b1 = (const float*)d_in[7];
  const float* W2 = (const float*)d_in[8];
  const float* b2 = (const float*)d_in[9];
  float* out = (float*)d_out;

  char* ws = (char*)d_ws;
  unsigned short* xb = (unsigned short*)ws;                       // 20,971,520 B
  unsigned short* Wb = (unsigned short*)(ws + 20971520);          //  6,553,600 B

  prep<<<23064, 256, 0, stream>>>(x, xb, Wc, Wb, b0, b1, b2, out);
  gemm_relu_dot<<<960, 256, 0, stream>>>(xb, Wb, bc, W0, W1, W2, out);
}